// Round 13
// baseline (3696.975 us; speedup 1.0000x reference)
//
#include <hip/hip_runtime.h>
#include <hip/hip_bf16.h>
#include <math.h>

// Problem constants
#define BSZ 64
#define TT  512
#define DD  512
#define UU  512
#define NZ  2048   // 4*U

#define NSL    32    // u-slices
#define USL    16    // units per slice
#define NBG    4     // batch groups
#define BG     16    // batches per group (= MFMA m)
#define KSTEPS 16    // 512 / 32 (MFMA k=32)

using short8  = __attribute__((ext_vector_type(8))) short;
using floatx4 = __attribute__((ext_vector_type(4))) float;
typedef unsigned long long u64;

__device__ __forceinline__ floatx4 mfma16(short8 a, short8 b, floatx4 c) {
  return __builtin_amdgcn_mfma_f32_16x16x32_bf16(a, b, c, 0, 0, 0);
}

// ---------------------------------------------------------------------------
// Wk (fp32 [K][N]) -> WkT bf16 [N][K] (transposed so B-fragments read 8
// contiguous k). Coalesced reads; each thread packs 8 k into one short8
// store. Output aliases the h_lo slab head (dead until the persist launch;
// kernels are stream-ordered). ~10us.
// ---------------------------------------------------------------------------
__global__ __launch_bounds__(256) void conv_wkt(const float* __restrict__ Wk,
                                                unsigned short* __restrict__ wkt) {
  const int n = blockIdx.x * 256 + threadIdx.x;
  const int k0 = blockIdx.y * 8;
  short8 v;
#pragma unroll
  for (int j = 0; j < 8; ++j) {
    __hip_bfloat16 h = __float2bfloat16(Wk[(size_t)(k0 + j) * NZ + n]);
    v[j] = *(const short*)&h;
  }
  *(short8*)(wkt + (size_t)n * DD + k0) = v;
}

// ---------------------------------------------------------------------------
// Phase 1: zx = x @ Wk via bf16 MFMA. M=32768, K=512, N=2048.
// R10 structure (proven: passed, ~180us) with conv_x FOLDED IN: A-operand is
// read as fp32 float4 pairs and converted to bf16 in-register during LDS
// staging (same rounding as the deleted conv_x pass; saves 128MB rd + 32MB
// wr + 32MB rd of the x_bf16 intermediate and one kernel launch).
// Tile 64x64, BK=32, 4 waves. Fragment conventions = persist kernel's
// (proven): A m=lane&15, kg=lane>>4; B n=lane&15; C row=(lane>>4)*4+r,
// col=lane&15. LDS stride 40 ushorts (16B-aligned b128, 2-way alias only).
// ---------------------------------------------------------------------------
__global__ __launch_bounds__(256) void gemm_zx_mfma(
    const float* __restrict__ x, const unsigned short* __restrict__ wkt,
    __hip_bfloat16* __restrict__ C) {
  __shared__ unsigned short As[64 * 40];
  __shared__ unsigned short Bs[64 * 40];

  const int tid = threadIdx.x;
  const int w = tid >> 6;
  const int lane = tid & 63;
  const int n0 = blockIdx.x * 64;
  const int m0 = blockIdx.y * 64;

  const int srow = tid >> 2;          // 0..63
  const int skq = tid & 3;            // 0..3 -> k-offset skq*8

  const int fm = (w * 16 + (lane & 15)) * 40 + (lane >> 4) * 8;  // A-frag idx
  const int fu = (lane & 15) * 40 + (lane >> 4) * 8;             // B-frag base

  floatx4 acc[4] = {{0, 0, 0, 0}, {0, 0, 0, 0}, {0, 0, 0, 0}, {0, 0, 0, 0}};

  for (int k0 = 0; k0 < DD; k0 += 32) {
    // A: fp32 -> bf16 in-register (replaces the conv_x pass)
    const float* xa = x + (size_t)(m0 + srow) * DD + k0 + skq * 8;
    const float4 a0v = *(const float4*)xa;
    const float4 a1v = *(const float4*)(xa + 4);
    short8 av;
    {
      const float va[8] = {a0v.x, a0v.y, a0v.z, a0v.w,
                           a1v.x, a1v.y, a1v.z, a1v.w};
#pragma unroll
      for (int j = 0; j < 8; ++j) {
        __hip_bfloat16 h = __float2bfloat16(va[j]);
        av[j] = *(const short*)&h;
      }
    }
    const short8 bv = *(const short8*)(wkt + (size_t)(n0 + srow) * DD + k0 + skq * 8);
    *(short8*)&As[srow * 40 + skq * 8] = av;
    *(short8*)&Bs[srow * 40 + skq * 8] = bv;
    __syncthreads();
    const short8 Af = *(const short8*)&As[fm];
#pragma unroll
    for (int ns = 0; ns < 4; ++ns) {
      const short8 Bf = *(const short8*)&Bs[ns * 16 * 40 + fu];
      acc[ns] = mfma16(Af, Bf, acc[ns]);
    }
    __syncthreads();
  }

  const int erow = m0 + w * 16 + (lane >> 4) * 4;
  const int ecol = n0 + (lane & 15);
#pragma unroll
  for (int ns = 0; ns < 4; ++ns)
#pragma unroll
    for (int r = 0; r < 4; ++r)
      C[(size_t)(erow + r) * NZ + ecol + ns * 16] = __float2bfloat16(acc[ns][r]);
}

// ---------------------------------------------------------------------------
// Phase 2: persistent LSTM kernel -- BYTE-IDENTICAL to R0/R10 (best measured:
// 3425us). Spread layout (NSL x NBG blocks), split-bf16 Wr MFMA, 32
// agent-scope flags + tid<NSL poll rendezvous.
// ---------------------------------------------------------------------------
template <bool ZXBF16>
__global__ __launch_bounds__(256) void lstm_persist(
    const void* __restrict__ zx_, const float* __restrict__ Wr,
    const float* __restrict__ bias, unsigned short* __restrict__ h_hi,
    unsigned short* __restrict__ h_lo, int* __restrict__ flags,
    float* __restrict__ out) {
  extern __shared__ char lds[];
  unsigned short* wr_hi = (unsigned short*)lds;            // [K][g][lane][8]
  unsigned short* wr_lo = wr_hi + KSTEPS * 4 * 64 * 8;     // 32768 ushorts each
  float* z_ex = (float*)(wr_lo + KSTEPS * 4 * 64 * 8);     // [4 g][16 b][16 u]

  const int sl = blockIdx.x;          // u-slice 0..31
  const int bg = blockIdx.y;          // batch group 0..3
  const int tid = threadIdx.x;
  const int g = tid >> 6;             // wave = gate 0..3
  const int lane = tid & 63;
  const int u0 = sl * USL;

  // ---- one-time: preformat Wr slice into LDS (split bf16, B-frag order) ----
  {
    const int cidx = tid & 63;        // gg*16+u within slice
    const int koff = tid >> 6;        // 0..3
    const int gg = cidx >> 4, u = cidx & 15;
    const int col = gg * UU + u0 + u;
    for (int k0 = 0; k0 < DD; k0 += 4) {
      const int k = k0 + koff;
      const float v = Wr[(size_t)k * NZ + col];
      const __hip_bfloat16 vh = __float2bfloat16(v);
      const float rem = v - __bfloat162float(vh);
      const __hip_bfloat16 vl = __float2bfloat16(rem);
      const int K = k >> 5, kg = (k >> 3) & 3, j = k & 7;
      const int off = ((K * 4 + gg) * 64 + (kg * 16 + u)) * 8 + j;
      wr_hi[off] = *(const unsigned short*)&vh;
      wr_lo[off] = *(const unsigned short*)&vl;
    }
  }
  __syncthreads();

  // MFMA A-fragment addressing: m = bg*16 + (lane&15), kgroup = lane>>4
  const int am = lane & 15, akg = lane >> 4;
  const size_t arow = (size_t)(bg * BG + am) * UU + akg * 8;  // ushort idx

  // epilogue mapping: thread -> (local batch eb, unit eu)
  const int eb = tid >> 4;            // 0..15
  const int eu = tid & 15;            // 0..15
  const int b = bg * BG + eb;         // global batch
  const float bias_i = bias[0 * UU + u0 + eu];
  const float bias_f = bias[1 * UU + u0 + eu];
  const float bias_g = bias[2 * UU + u0 + eu];
  const float bias_o = bias[3 * UU + u0 + eu];
  float c_state = 0.f;
  const size_t plane_t = (size_t)BSZ * UU;          // 32768 ushorts / timestep
  const int wword = (b * UU + u0 + eu) >> 1;

  int* myflag = flags + (bg * NSL + sl) * 16;

  for (int t = 0; t < TT; ++t) {
    // ---- zx prefetch for this step (independent of h_t) ----
    float zi, zf, zg, zo;
    {
      const size_t zb = ((size_t)b * TT + t) * NZ + u0 + eu;
      if constexpr (ZXBF16) {
        const unsigned short* zx = (const unsigned short*)zx_;
        zi = __bfloat162float(*(const __hip_bfloat16*)&zx[zb + 0 * UU]);
        zf = __bfloat162float(*(const __hip_bfloat16*)&zx[zb + 1 * UU]);
        zg = __bfloat162float(*(const __hip_bfloat16*)&zx[zb + 2 * UU]);
        zo = __bfloat162float(*(const __hip_bfloat16*)&zx[zb + 3 * UU]);
      } else {
        const float* zx = (const float*)zx_;
        zi = zx[zb + 0 * UU];
        zf = zx[zb + 1 * UU];
        zg = zx[zb + 2 * UU];
        zo = zx[zb + 3 * UU];
      }
    }

    // ---- acquire h_t: relaxed poll of this bg's 32 flags, then wg fence ----
    if (tid < NSL) {
      const int* fp = flags + (bg * NSL + tid) * 16;
      while (__hip_atomic_load(fp, __ATOMIC_RELAXED, __HIP_MEMORY_SCOPE_AGENT) < t) {
      }
    }
    __syncthreads();
    __builtin_amdgcn_fence(__ATOMIC_ACQUIRE, "workgroup");

    // ---- z[16b][16u] for gate g via split-bf16 MFMA ----
    const unsigned short* Ahi = h_hi + (size_t)t * plane_t + arow;
    const unsigned short* Alo = h_lo + (size_t)t * plane_t + arow;
    floatx4 a0 = {0, 0, 0, 0}, a1 = {0, 0, 0, 0}, a2 = {0, 0, 0, 0};
#pragma unroll 4
    for (int K = 0; K < KSTEPS; ++K) {
      const short8 ahi = *(const short8*)(Ahi + K * 32);
      const short8 alo = *(const short8*)(Alo + K * 32);
      const short8 bhi = *(const short8*)(wr_hi + ((K * 4 + g) * 64 + lane) * 8);
      const short8 blo = *(const short8*)(wr_lo + ((K * 4 + g) * 64 + lane) * 8);
      a0 = mfma16(ahi, bhi, a0);
      a1 = mfma16(ahi, blo, a1);
      a2 = mfma16(alo, bhi, a2);
    }
    // C layout: u = lane&15, b-in-tile = (lane>>4)*4 + r
#pragma unroll
    for (int r = 0; r < 4; ++r) {
      const int bb = (lane >> 4) * 4 + r;
      z_ex[(g * 16 + bb) * 16 + (lane & 15)] = a0[r] + a1[r] + a2[r];
    }
    __syncthreads();

    // ---- pointwise gates: thread = (eb, eu) ----
    zi += z_ex[(0 * 16 + eb) * 16 + eu] + bias_i;
    zf += z_ex[(1 * 16 + eb) * 16 + eu] + bias_f;
    zg += z_ex[(2 * 16 + eb) * 16 + eu] + bias_g;
    zo += z_ex[(3 * 16 + eb) * 16 + eu] + bias_o;

    const float ig = 1.f / (1.f + expf(-zi));
    const float fg = 1.f / (1.f + expf(-zf));
    const float gg = tanhf(zg);
    const float og = 1.f / (1.f + expf(-zo));
    c_state = fg * c_state + ig * gg;
    const float hn = og * tanhf(c_state);

    // split-bf16; pack pair-words via shfl, even threads store (32-bit atomics)
    const __hip_bfloat16 hh = __float2bfloat16(hn);
    const float hrem = hn - __bfloat162float(hh);
    const __hip_bfloat16 hl = __float2bfloat16(hrem);
    const unsigned int vhi = (unsigned int)*(const unsigned short*)&hh;
    const unsigned int vlo = (unsigned int)*(const unsigned short*)&hl;
    const unsigned int phi_n = (unsigned int)__shfl_xor((int)vhi, 1);
    const unsigned int plo_n = (unsigned int)__shfl_xor((int)vlo, 1);
    if ((tid & 1) == 0) {
      const unsigned int whi = vhi | (phi_n << 16);
      const unsigned int wlo = vlo | (plo_n << 16);
      unsigned int* phi = (unsigned int*)(h_hi + (size_t)(t + 1) * plane_t) + wword;
      unsigned int* plo = (unsigned int*)(h_lo + (size_t)(t + 1) * plane_t) + wword;
      __hip_atomic_store(phi, whi, __ATOMIC_RELAXED, __HIP_MEMORY_SCOPE_AGENT);
      __hip_atomic_store(plo, wlo, __ATOMIC_RELAXED, __HIP_MEMORY_SCOPE_AGENT);
    }

    if (t == TT - 1) out[(size_t)b * UU + u0 + eu] = hn;

    // ---- release: barrier drains vmcnt (stores at coherence point) ----
    __syncthreads();
    if (tid == 0)
      __hip_atomic_store(myflag, t + 1, __ATOMIC_RELAXED,
                         __HIP_MEMORY_SCOPE_AGENT);
  }
}

// ---------------------------------------------------------------------------
extern "C" void kernel_launch(void* const* d_in, const int* in_sizes, int n_in,
                              void* d_out, int out_size, void* d_ws, size_t ws_size,
                              hipStream_t stream) {
  const float* x    = (const float*)d_in[0];
  const float* Wk   = (const float*)d_in[1];
  const float* Wr   = (const float*)d_in[2];
  const float* bias = (const float*)d_in[3];
  float* out = (float*)d_out;

  const size_t plane_t = (size_t)BSZ * UU;                      // 32768
  const size_t hplane_bytes = (size_t)(TT + 1) * plane_t * 2;   // 32.06 MiB
  const size_t flags_bytes = (size_t)NBG * NSL * 16 * 4;        // 8 KiB
  const size_t zx_bytes = (size_t)BSZ * TT * NZ * 2;            // 128 MiB (bf16)

  char* ws = (char*)d_ws;
  __hip_bfloat16* zx = (__hip_bfloat16*)ws;
  unsigned short* h_hi = (unsigned short*)(ws + zx_bytes);
  unsigned short* h_lo = (unsigned short*)(ws + zx_bytes + hplane_bytes);
  int* flags = (int*)(ws + zx_bytes + 2 * hplane_bytes);

  // WkT (2 MiB) aliases the h_lo slab head -- dead after the gemm; the
  // h_0/flags memsets and persist launch are stream-ordered after it.
  unsigned short* wkt = h_lo;

  // 1) Wk -> WkT bf16 (transposed, contiguous-k B-frags)
  conv_wkt<<<dim3(NZ / 256, DD / 8), 256, 0, stream>>>(Wk, wkt);

  // 2) zx = x @ Wk via bf16 MFMA (x converted fp32->bf16 in-register)
  gemm_zx_mfma<<<dim3(NZ / 64, (BSZ * TT) / 64), 256, 0, stream>>>(x, wkt, zx);

  // 3) init h_0 plane + flags (after the gemm: wkt alias now dead)
  hipMemsetAsync(h_hi, 0, plane_t * 2, stream);
  hipMemsetAsync(h_lo, 0, plane_t * 2, stream);
  hipMemsetAsync(flags, 0, flags_bytes, stream);

  // 4) persistent LSTM (R0/R10 config, byte-identical)
  const int lds_bytes = KSTEPS * 4 * 64 * 8 * 2 * 2 + 4 * 16 * 16 * 4;  // 135168
  dim3 pgrid(NSL, NBG);
  hipFuncSetAttribute(reinterpret_cast<const void*>(lstm_persist<true>),
                      hipFuncAttributeMaxDynamicSharedMemorySize, lds_bytes);
  lstm_persist<true><<<pgrid, 256, lds_bytes, stream>>>(zx, Wr, bias, h_hi, h_lo,
                                                        flags, out);
}